// Round 12
// baseline (65.411 us; speedup 1.0000x reference)
//
#include <hip/hip_runtime.h>
#include <math.h>

#define H 1024
#define S 20
#define V 50257
#define KC_BLOCKS 512
#define KC_WAVES (KC_BLOCKS * 8)  // 4096 waves

__device__ __forceinline__ float wave_reduce_sum(float v) {
  #pragma unroll
  for (int off = 32; off > 0; off >>= 1)
    v += __shfl_xor(v, off, 64);
  return v;
}

// ============ kA: ALL softmax-independent streaming (44 MB, fully parallel) ==
// b in [0,256):     attention energy -> bpart[S][256]
// b in [256,1024):  gie[W] = dot(w_ih[W][0:H], embed) + b_ih[W]
// b in [1024,1792): E[s][W] = dot(w_ih[W][H:2H], enc[s])  (s=0..19)
// b in [1792,2560): ghv[W] = dot(w_hh[W], hidden) + b_hh[W]
__global__ __launch_bounds__(256) void kA(
    const int* __restrict__ token,
    const float* __restrict__ hidden,
    const float* __restrict__ enc,
    const float* __restrict__ embed_table,
    const float* __restrict__ attn_w,
    const float* __restrict__ attn_b,
    const float* __restrict__ v_w,
    const float* __restrict__ w_ih,
    const float* __restrict__ w_hh,
    const float* __restrict__ b_ih,
    const float* __restrict__ b_hh,
    float* __restrict__ bpart,   // [S][256]
    float* __restrict__ gie,     // [3H]
    float* __restrict__ Emat,    // [S][3H]
    float* __restrict__ ghv)     // [3H]
{
  __shared__ float esh[4][S];
  const int t = threadIdx.x;
  const int lane = t & 63;
  const int wv = t >> 6;
  const int b = blockIdx.x;

  if (b < 256) {
    const int j = b * 4 + wv;
    const float* wrow = attn_w + (size_t)j * (2 * H);
    float4 wlo[4], whi[4], hid4[4];
    #pragma unroll
    for (int q = 0; q < 4; ++q) {
      const int idx = lane + 64 * q;
      wlo[q]  = ((const float4*)wrow)[idx];
      whi[q]  = ((const float4*)(wrow + H))[idx];
      hid4[q] = ((const float4*)hidden)[idx];
    }
    float hp = 0.f;
    #pragma unroll
    for (int q = 0; q < 4; ++q)
      hp += wlo[q].x * hid4[q].x + wlo[q].y * hid4[q].y +
            wlo[q].z * hid4[q].z + wlo[q].w * hid4[q].w;
    hp = wave_reduce_sum(hp);

    float myval = 0.f;
    #pragma unroll
    for (int s = 0; s < S; ++s) {
      const float4* e4 = (const float4*)(enc + s * H);
      float es = 0.f;
      #pragma unroll
      for (int q = 0; q < 4; ++q) {
        const float4 e = e4[lane + 64 * q];
        es += whi[q].x * e.x + whi[q].y * e.y + whi[q].z * e.z + whi[q].w * e.w;
      }
      es = wave_reduce_sum(es);
      if (lane == s) myval = es;
    }
    if (lane < S)
      esh[wv][lane] = tanhf(hp + myval + attn_b[j]) * v_w[j];
    __syncthreads();
    if (wv == 0 && lane < S)
      bpart[lane * 256 + b] =
          esh[0][lane] + esh[1][lane] + esh[2][lane] + esh[3][lane];
  } else if (b < 1024) {
    const int W = (b - 256) * 4 + wv;
    const float* wr = w_ih + (size_t)W * (2 * H);
    const float* embed = embed_table + (size_t)(*token) * H;
    float a = 0.f;
    #pragma unroll
    for (int q = 0; q < 4; ++q) {
      const int idx = lane + 64 * q;
      const float4 w = ((const float4*)wr)[idx];
      const float4 e = ((const float4*)embed)[idx];
      a += w.x * e.x + w.y * e.y + w.z * e.z + w.w * e.w;
    }
    a = wave_reduce_sum(a);
    if (lane == 0) gie[W] = a + b_ih[W];
  } else if (b < 1792) {
    const int W = (b - 1024) * 4 + wv;
    const float* wr = w_ih + (size_t)W * (2 * H) + H;
    float4 wv4[4];
    #pragma unroll
    for (int q = 0; q < 4; ++q) wv4[q] = ((const float4*)wr)[lane + 64 * q];
    float myE = 0.f;
    #pragma unroll
    for (int s = 0; s < S; ++s) {
      const float4* e4 = (const float4*)(enc + s * H);
      float es = 0.f;
      #pragma unroll
      for (int q = 0; q < 4; ++q) {
        const float4 e = e4[lane + 64 * q];
        es += wv4[q].x * e.x + wv4[q].y * e.y + wv4[q].z * e.z + wv4[q].w * e.w;
      }
      es = wave_reduce_sum(es);
      if (lane == s) myE = es;
    }
    if (lane < S) Emat[lane * (3 * H) + W] = myE;
  } else {
    const int W = (b - 1792) * 4 + wv;
    const float* wr = w_hh + (size_t)W * H;
    float a = 0.f;
    #pragma unroll
    for (int q = 0; q < 4; ++q) {
      const int idx = lane + 64 * q;
      const float4 w = ((const float4*)wr)[idx];
      const float4 h = ((const float4*)hidden)[idx];
      a += w.x * h.x + w.y * h.y + w.z * h.z + w.w * h.w;
    }
    a = wave_reduce_sum(a);
    if (lane == 0) ghv[W] = a + b_hh[W];
  }
}

// ============ kB': tiny softmax + E-combine + gates -> hnew ============
// 2 blocks x 512 threads; thread owns j = b*512 + t. All reads L2/L3-hot.
__global__ __launch_bounds__(512) void kB2(
    const float* __restrict__ bpart,    // [S][256]
    const float* __restrict__ gie,      // [3H]
    const float* __restrict__ Emat,     // [S][3H]
    const float* __restrict__ ghv,      // [3H]
    const float* __restrict__ hidden,   // [H]
    float* __restrict__ hnew,           // [H]
    float* __restrict__ out)            // out[V..V+H) gets hnew
{
  __shared__ float scores_sh[S];
  __shared__ float attn_sh[S];
  const int t = threadIdx.x;
  const int lane = t & 63;
  const int wv = t >> 6;
  const int j = blockIdx.x * 512 + t;

  for (int s = wv; s < S; s += 8) {
    const float4 p = ((const float4*)(bpart + s * 256))[lane];
    float v = wave_reduce_sum(p.x + p.y + p.z + p.w);
    if (lane == 0) scores_sh[s] = v;
  }
  __syncthreads();
  if (t == 0) {
    float m = -1e30f;
    for (int s = 0; s < S; ++s) m = fmaxf(m, scores_sh[s]);
    float sum = 0.f;
    for (int s = 0; s < S; ++s) {
      const float e = expf(scores_sh[s] - m);
      attn_sh[s] = e;
      sum += e;
    }
    const float inv = 1.f / sum;
    for (int s = 0; s < S; ++s) attn_sh[s] *= inv;
  }
  __syncthreads();

  float g0 = 0.f, g1 = 0.f, g2 = 0.f;
  #pragma unroll
  for (int s = 0; s < S; ++s) {
    const float a = attn_sh[s];
    const float* Es = Emat + s * (3 * H);
    g0 += a * Es[j];
    g1 += a * Es[H + j];
    g2 += a * Es[2 * H + j];
  }
  const float i_r = gie[j]         + g0;
  const float i_z = gie[H + j]     + g1;
  const float i_n = gie[2 * H + j] + g2;
  const float h_r = ghv[j];
  const float h_z = ghv[H + j];
  const float h_n = ghv[2 * H + j];
  const float rr = 1.f / (1.f + expf(-(i_r + h_r)));
  const float zz = 1.f / (1.f + expf(-(i_z + h_z)));
  const float nn = tanhf(i_n + rr * h_n);
  const float hn = (1.f - zz) * nn + zz * hidden[j];
  hnew[j] = hn;
  out[V + j] = hn;
}

// ============ kC: balanced-chunk streaming logits, 6 rows/group ==========
// 512 blocks x 512 threads, 2 blocks/CU. Wave gw owns rows
// [gw*V/4096, (gw+1)*V/4096) -- 12 or 13 rows = 2x6 (+<=1 remainder).
__global__ __launch_bounds__(512, 4) void kC(
    const float* __restrict__ hnew,
    const float* __restrict__ out_w,    // [V][H]
    const float* __restrict__ out_b,    // [V]
    float* __restrict__ out,            // logits
    float* __restrict__ pmax,           // [KC_BLOCKS]
    float* __restrict__ psum)           // [KC_BLOCKS]
{
  __shared__ float stat_m[8];
  __shared__ float stat_s[8];
  const int t = threadIdx.x;
  const int lane = t & 63;
  const int wv = t >> 6;
  const int b = blockIdx.x;
  const long long gw = b * 8 + wv;

  float4 h4[4];
  #pragma unroll
  for (int q = 0; q < 4; ++q)
    h4[q] = ((const float4*)hnew)[lane + 64 * q];

  const int r0 = (int)((gw * V) / KC_WAVES);
  const int r1 = (int)(((gw + 1) * V) / KC_WAVES);

  float wm = -INFINITY, wsum = 0.f;

  int r = r0;
  for (; r + 6 <= r1; r += 6) {
    float acc[6];
    #pragma unroll
    for (int k = 0; k < 6; ++k) acc[k] = 0.f;
    #pragma unroll
    for (int q = 0; q < 4; ++q) {
      const int idx = lane + 64 * q;
      #pragma unroll
      for (int k = 0; k < 6; ++k) {
        const float4 w = ((const float4*)(out_w + (size_t)(r + k) * H))[idx];
        acc[k] += w.x * h4[q].x + w.y * h4[q].y + w.z * h4[q].z + w.w * h4[q].w;
      }
    }
    float vals[6];
    #pragma unroll
    for (int k = 0; k < 6; ++k)
      vals[k] = wave_reduce_sum(acc[k]) + out_b[r + k];

    // lanes 0-5 store (vals wave-uniform after reduce)
    float vv = vals[5];
    #pragma unroll
    for (int k = 4; k >= 0; --k) vv = (lane == k) ? vals[k] : vv;
    if (lane < 6) out[r + lane] = vv;

    float gm = vals[0];
    #pragma unroll
    for (int k = 1; k < 6; ++k) gm = fmaxf(gm, vals[k]);
    const float M2 = fmaxf(wm, gm);
    float add = 0.f;
    #pragma unroll
    for (int k = 0; k < 6; ++k) add += expf(vals[k] - M2);
    wsum = wsum * expf(wm - M2) + add;
    wm = M2;
  }
  for (; r < r1; ++r) {
    const float4* p0 = (const float4*)(out_w + (size_t)r * H);
    float a0 = 0.f;
    #pragma unroll
    for (int q = 0; q < 4; ++q) {
      const float4 w0 = p0[lane + 64 * q];
      a0 += w0.x * h4[q].x + w0.y * h4[q].y + w0.z * h4[q].z + w0.w * h4[q].w;
    }
    a0 = wave_reduce_sum(a0);
    const float val0 = a0 + out_b[r];
    if (lane == 0) out[r] = val0;
    const float M2 = fmaxf(wm, val0);
    wsum = wsum * expf(wm - M2) + expf(val0 - M2);
    wm = M2;
  }

  if (lane == 0) { stat_m[wv] = wm; stat_s[wv] = wsum; }
  __syncthreads();
  if (t == 0) {
    float M = stat_m[0], Ss = stat_s[0];
    #pragma unroll
    for (int i = 1; i < 8; ++i) {
      const float m2 = stat_m[i], s2 = stat_s[i];
      const float M2 = fmaxf(M, m2);
      Ss = Ss * expf(M - M2) + s2 * expf(m2 - M2);
      M = M2;
    }
    pmax[b] = M;
    psum[b] = Ss;
  }
}

// ============ kD: block-redundant stat reduce + subtract ============
__global__ __launch_bounds__(512) void kD(
    const float* __restrict__ pmax,
    const float* __restrict__ psum,
    float* __restrict__ out)
{
  __shared__ float sm[8];
  __shared__ float ss[8];
  __shared__ float Tsh;
  const int t = threadIdx.x, lane = t & 63, wv = t >> 6;

  float dm = pmax[t];
  float dsv = psum[t];
  #pragma unroll
  for (int off = 32; off > 0; off >>= 1) {
    const float m2 = __shfl_xor(dm, off, 64);
    const float s2 = __shfl_xor(dsv, off, 64);
    const float M2 = fmaxf(dm, m2);
    dsv = dsv * expf(dm - M2) + s2 * expf(m2 - M2);
    dm = M2;
  }
  if (lane == 0) { sm[wv] = dm; ss[wv] = dsv; }
  __syncthreads();
  if (t == 0) {
    float M = sm[0], Ss = ss[0];
    #pragma unroll
    for (int i = 1; i < 8; ++i) {
      const float m2 = sm[i], s2 = ss[i];
      const float M2 = fmaxf(M, m2);
      Ss = Ss * expf(M - M2) + s2 * expf(m2 - M2);
      M = M2;
    }
    Tsh = M + logf(Ss);
  }
  __syncthreads();
  const float T = Tsh;
  const int i = blockIdx.x * 512 + t;
  if (i < V) out[i] -= T;
}

extern "C" void kernel_launch(void* const* d_in, const int* in_sizes, int n_in,
                              void* d_out, int out_size, void* d_ws, size_t ws_size,
                              hipStream_t stream) {
  const int*   token       = (const int*)d_in[0];
  const float* hidden      = (const float*)d_in[1];
  const float* enc         = (const float*)d_in[2];
  const float* embed_table = (const float*)d_in[3];
  const float* attn_w      = (const float*)d_in[4];
  const float* attn_b      = (const float*)d_in[5];
  const float* v_w         = (const float*)d_in[6];
  const float* w_ih        = (const float*)d_in[7];
  const float* w_hh        = (const float*)d_in[8];
  const float* b_ih        = (const float*)d_in[9];
  const float* b_hh        = (const float*)d_in[10];
  const float* out_w       = (const float*)d_in[11];
  const float* out_b       = (const float*)d_in[12];
  float* out = (float*)d_out;
  float* ws  = (float*)d_ws;

  // ws layout (floats)
  float* bpart = ws;            // 5120
  float* gie   = ws + 5120;     // 3072
  float* ghv   = ws + 8192;     // 3072
  float* Emat  = ws + 11264;    // S*3H = 61440
  float* hnew  = ws + 72704;    // 1024
  float* pmax  = ws + 73728;    // 512
  float* psum  = ws + 74240;    // 512

  kA<<<2560, 256, 0, stream>>>(token, hidden, enc, embed_table, attn_w, attn_b,
                               v_w, w_ih, w_hh, b_ih, b_hh, bpart, gie, Emat, ghv);
  kB2<<<2, 512, 0, stream>>>(bpart, gie, Emat, ghv, hidden, hnew, out);
  kC<<<KC_BLOCKS, 512, 0, stream>>>(hnew, out_w, out_b, out, pmax, psum);
  kD<<<(V + 511) / 512, 512, 0, stream>>>(pmax, psum, out);
}

// Round 13
// 58.459 us; speedup vs baseline: 1.1189x; 1.1189x over previous
//
#include <hip/hip_runtime.h>
#include <math.h>

#define H 1024
#define S 20
#define V 50257
#define KC_BLOCKS 512
#define KC_WAVES (KC_BLOCKS * 8)  // 4096 waves

__device__ __forceinline__ float wave_reduce_sum(float v) {
  #pragma unroll
  for (int off = 32; off > 0; off >>= 1)
    v += __shfl_xor(v, off, 64);
  return v;
}

// ============ kA: independent streaming work (32 MB) ============
// b in [0,256):    attention energy -> bpart[S][256]
// b in [256,1024): gie[W] = dot(w_ih[W][0:H], embed) + b_ih[W]
// b in [1024,1792): ghv[W] = dot(w_hh[W], hidden) + b_hh[W]
__global__ __launch_bounds__(256) void kA(
    const int* __restrict__ token,
    const float* __restrict__ hidden,
    const float* __restrict__ enc,
    const float* __restrict__ embed_table,
    const float* __restrict__ attn_w,
    const float* __restrict__ attn_b,
    const float* __restrict__ v_w,
    const float* __restrict__ w_ih,
    const float* __restrict__ w_hh,
    const float* __restrict__ b_ih,
    const float* __restrict__ b_hh,
    float* __restrict__ bpart,   // [S][256]
    float* __restrict__ gie,     // [3H]
    float* __restrict__ ghv)     // [3H]
{
  __shared__ float esh[4][S];
  const int t = threadIdx.x;
  const int lane = t & 63;
  const int wv = t >> 6;
  const int b = blockIdx.x;

  if (b < 256) {
    const int j = b * 4 + wv;
    const float* wrow = attn_w + (size_t)j * (2 * H);
    float4 wlo[4], whi[4], hid4[4];
    #pragma unroll
    for (int q = 0; q < 4; ++q) {
      const int idx = lane + 64 * q;
      wlo[q]  = ((const float4*)wrow)[idx];
      whi[q]  = ((const float4*)(wrow + H))[idx];
      hid4[q] = ((const float4*)hidden)[idx];
    }
    float hp = 0.f;
    #pragma unroll
    for (int q = 0; q < 4; ++q)
      hp += wlo[q].x * hid4[q].x + wlo[q].y * hid4[q].y +
            wlo[q].z * hid4[q].z + wlo[q].w * hid4[q].w;
    hp = wave_reduce_sum(hp);

    float myval = 0.f;
    #pragma unroll
    for (int s = 0; s < S; ++s) {
      const float4* e4 = (const float4*)(enc + s * H);
      float es = 0.f;
      #pragma unroll
      for (int q = 0; q < 4; ++q) {
        const float4 e = e4[lane + 64 * q];
        es += whi[q].x * e.x + whi[q].y * e.y + whi[q].z * e.z + whi[q].w * e.w;
      }
      es = wave_reduce_sum(es);
      if (lane == s) myval = es;
    }
    if (lane < S)
      esh[wv][lane] = tanhf(hp + myval + attn_b[j]) * v_w[j];
    __syncthreads();
    if (wv == 0 && lane < S)
      bpart[lane * 256 + b] =
          esh[0][lane] + esh[1][lane] + esh[2][lane] + esh[3][lane];
  } else if (b < 1024) {
    const int W = (b - 256) * 4 + wv;
    const float* wr = w_ih + (size_t)W * (2 * H);
    const float* embed = embed_table + (size_t)(*token) * H;
    float a = 0.f;
    #pragma unroll
    for (int q = 0; q < 4; ++q) {
      const int idx = lane + 64 * q;
      const float4 w = ((const float4*)wr)[idx];
      const float4 e = ((const float4*)embed)[idx];
      a += w.x * e.x + w.y * e.y + w.z * e.z + w.w * e.w;
    }
    a = wave_reduce_sum(a);
    if (lane == 0) gie[W] = a + b_ih[W];
  } else {
    const int W = (b - 1024) * 4 + wv;
    const float* wr = w_hh + (size_t)W * H;
    float a = 0.f;
    #pragma unroll
    for (int q = 0; q < 4; ++q) {
      const int idx = lane + 64 * q;
      const float4 w = ((const float4*)wr)[idx];
      const float4 h = ((const float4*)hidden)[idx];
      a += w.x * h.x + w.y * h.y + w.z * h.z + w.w * h.w;
    }
    a = wave_reduce_sum(a);
    if (lane == 0) ghv[W] = a + b_hh[W];
  }
}

// ============ kB: redundant softmax+context, 3 ctx rows/wave, gates -> hnew ==
__global__ __launch_bounds__(256) void kB(
    const float* __restrict__ enc,
    const float* __restrict__ bpart,
    const float* __restrict__ w_ih,
    const float* __restrict__ gie,
    const float* __restrict__ ghv,
    const float* __restrict__ hidden,
    float* __restrict__ hnew,
    float* __restrict__ out)      // out[V..V+H) gets hnew
{
  __shared__ float scores_sh[S];
  __shared__ float attn_sh[S];
  __shared__ float wsh[H];
  const int t = threadIdx.x;
  const int lane = t & 63;
  const int wv = t >> 6;
  const int j = blockIdx.x * 4 + wv;

  for (int s = wv; s < S; s += 4) {
    const float4 p = ((const float4*)(bpart + s * 256))[lane];
    float v = wave_reduce_sum(p.x + p.y + p.z + p.w);
    if (lane == 0) scores_sh[s] = v;
  }
  __syncthreads();
  if (t == 0) {
    float m = -1e30f;
    for (int s = 0; s < S; ++s) m = fmaxf(m, scores_sh[s]);
    float sum = 0.f;
    for (int s = 0; s < S; ++s) {
      const float e = expf(scores_sh[s] - m);
      attn_sh[s] = e;
      sum += e;
    }
    const float inv = 1.f / sum;
    for (int s = 0; s < S; ++s) attn_sh[s] *= inv;
  }
  __syncthreads();
  for (int h = t; h < H; h += 256) {
    float acc = 0.f;
    #pragma unroll
    for (int s = 0; s < S; ++s) acc += attn_sh[s] * enc[s * H + h];
    wsh[h] = acc;
  }
  __syncthreads();

  float4 c4[4];
  #pragma unroll
  for (int q = 0; q < 4; ++q) c4[q] = ((const float4*)wsh)[lane + 64 * q];

  float gict[3];
  #pragma unroll
  for (int g = 0; g < 3; ++g) {
    const float* wr = w_ih + (size_t)(g * H + j) * (2 * H) + H;
    float a = 0.f;
    #pragma unroll
    for (int q = 0; q < 4; ++q) {
      const float4 w = ((const float4*)wr)[lane + 64 * q];
      a += w.x * c4[q].x + w.y * c4[q].y + w.z * c4[q].z + w.w * c4[q].w;
    }
    gict[g] = wave_reduce_sum(a);
  }

  if (lane == 0) {
    const float i_r = gie[j]         + gict[0];
    const float i_z = gie[H + j]     + gict[1];
    const float i_n = gie[2 * H + j] + gict[2];
    const float h_r = ghv[j];
    const float h_z = ghv[H + j];
    const float h_n = ghv[2 * H + j];
    const float r = 1.f / (1.f + expf(-(i_r + h_r)));
    const float z = 1.f / (1.f + expf(-(i_z + h_z)));
    const float n = tanhf(i_n + r * h_n);
    const float hn = (1.f - z) * n + z * hidden[j];
    hnew[j] = hn;
    out[V + j] = hn;
  }
}

// ============ kC: balanced-chunk streaming logits, 2 rows/group, hi-occ ======
// 512 blocks x 512 threads, __launch_bounds__(512,8) caps VGPR at 64 ->
// up to 32 waves/CU for latency hiding. Wave gw owns rows
// [gw*V/4096, (gw+1)*V/4096) -- 12 or 13 rows = 6x2 (+<=1 remainder).
__global__ __launch_bounds__(512, 8) void kC(
    const float* __restrict__ hnew,
    const float* __restrict__ out_w,    // [V][H]
    const float* __restrict__ out_b,    // [V]
    float* __restrict__ out,            // logits
    float* __restrict__ pmax,           // [KC_BLOCKS]
    float* __restrict__ psum)           // [KC_BLOCKS]
{
  __shared__ float stat_m[8];
  __shared__ float stat_s[8];
  const int t = threadIdx.x;
  const int lane = t & 63;
  const int wv = t >> 6;
  const int b = blockIdx.x;
  const long long gw = b * 8 + wv;

  float4 h4[4];
  #pragma unroll
  for (int q = 0; q < 4; ++q)
    h4[q] = ((const float4*)hnew)[lane + 64 * q];

  const int r0 = (int)((gw * V) / KC_WAVES);
  const int r1 = (int)(((gw + 1) * V) / KC_WAVES);

  float wm = -INFINITY, wsum = 0.f;

  int r = r0;
  for (; r + 2 <= r1; r += 2) {
    const float4* p0 = (const float4*)(out_w + (size_t)(r + 0) * H);
    const float4* p1 = (const float4*)(out_w + (size_t)(r + 1) * H);
    float a0 = 0.f, a1 = 0.f;
    #pragma unroll
    for (int q = 0; q < 4; ++q) {
      const int idx = lane + 64 * q;
      const float4 w0 = p0[idx];
      const float4 w1 = p1[idx];
      a0 += w0.x * h4[q].x + w0.y * h4[q].y + w0.z * h4[q].z + w0.w * h4[q].w;
      a1 += w1.x * h4[q].x + w1.y * h4[q].y + w1.z * h4[q].z + w1.w * h4[q].w;
    }
    a0 = wave_reduce_sum(a0);
    a1 = wave_reduce_sum(a1);
    const float val0 = a0 + out_b[r + 0];
    const float val1 = a1 + out_b[r + 1];

    const float vv = (lane == 0) ? val0 : val1;
    if (lane < 2) out[r + lane] = vv;

    const float gm = fmaxf(val0, val1);
    const float M2 = fmaxf(wm, gm);
    wsum = wsum * expf(wm - M2) + expf(val0 - M2) + expf(val1 - M2);
    wm = M2;
  }
  for (; r < r1; ++r) {
    const float4* p0 = (const float4*)(out_w + (size_t)r * H);
    float a0 = 0.f;
    #pragma unroll
    for (int q = 0; q < 4; ++q) {
      const float4 w0 = p0[lane + 64 * q];
      a0 += w0.x * h4[q].x + w0.y * h4[q].y + w0.z * h4[q].z + w0.w * h4[q].w;
    }
    a0 = wave_reduce_sum(a0);
    const float val0 = a0 + out_b[r];
    if (lane == 0) out[r] = val0;
    const float M2 = fmaxf(wm, val0);
    wsum = wsum * expf(wm - M2) + expf(val0 - M2);
    wm = M2;
  }

  if (lane == 0) { stat_m[wv] = wm; stat_s[wv] = wsum; }
  __syncthreads();
  if (t == 0) {
    float M = stat_m[0], Ss = stat_s[0];
    #pragma unroll
    for (int i = 1; i < 8; ++i) {
      const float m2 = stat_m[i], s2 = stat_s[i];
      const float M2 = fmaxf(M, m2);
      Ss = Ss * expf(M - M2) + s2 * expf(m2 - M2);
      M = M2;
    }
    pmax[b] = M;
    psum[b] = Ss;
  }
}

// ============ kD: block-redundant stat reduce + subtract ============
__global__ __launch_bounds__(512) void kD(
    const float* __restrict__ pmax,
    const float* __restrict__ psum,
    float* __restrict__ out)
{
  __shared__ float sm[8];
  __shared__ float ss[8];
  __shared__ float Tsh;
  const int t = threadIdx.x, lane = t & 63, wv = t >> 6;

  float dm = pmax[t];
  float dsv = psum[t];
  #pragma unroll
  for (int off = 32; off > 0; off >>= 1) {
    const float m2 = __shfl_xor(dm, off, 64);
    const float s2 = __shfl_xor(dsv, off, 64);
    const float M2 = fmaxf(dm, m2);
    dsv = dsv * expf(dm - M2) + s2 * expf(m2 - M2);
    dm = M2;
  }
  if (lane == 0) { sm[wv] = dm; ss[wv] = dsv; }
  __syncthreads();
  if (t == 0) {
    float M = sm[0], Ss = ss[0];
    #pragma unroll
    for (int i = 1; i < 8; ++i) {
      const float m2 = sm[i], s2 = ss[i];
      const float M2 = fmaxf(M, m2);
      Ss = Ss * expf(M - M2) + s2 * expf(m2 - M2);
      M = M2;
    }
    Tsh = M + logf(Ss);
  }
  __syncthreads();
  const float T = Tsh;
  const int i = blockIdx.x * 512 + t;
  if (i < V) out[i] -= T;
}

extern "C" void kernel_launch(void* const* d_in, const int* in_sizes, int n_in,
                              void* d_out, int out_size, void* d_ws, size_t ws_size,
                              hipStream_t stream) {
  const int*   token       = (const int*)d_in[0];
  const float* hidden      = (const float*)d_in[1];
  const float* enc         = (const float*)d_in[2];
  const float* embed_table = (const float*)d_in[3];
  const float* attn_w      = (const float*)d_in[4];
  const float* attn_b      = (const float*)d_in[5];
  const float* v_w         = (const float*)d_in[6];
  const float* w_ih        = (const float*)d_in[7];
  const float* w_hh        = (const float*)d_in[8];
  const float* b_ih        = (const float*)d_in[9];
  const float* b_hh        = (const float*)d_in[10];
  const float* out_w       = (const float*)d_in[11];
  const float* out_b       = (const float*)d_in[12];
  float* out = (float*)d_out;
  float* ws  = (float*)d_ws;

  // ws layout (floats)
  float* bpart = ws;           // 5120
  float* gie   = ws + 5120;    // 3072
  float* ghv   = ws + 8192;    // 3072
  float* hnew  = ws + 11264;   // 1024
  float* pmax  = ws + 12288;   // 512
  float* psum  = ws + 12800;   // 512

  kA<<<1792, 256, 0, stream>>>(token, hidden, enc, embed_table, attn_w, attn_b,
                               v_w, w_ih, w_hh, b_ih, b_hh, bpart, gie, ghv);
  kB<<<256, 256, 0, stream>>>(enc, bpart, w_ih, gie, ghv, hidden, hnew, out);
  kC<<<KC_BLOCKS, 512, 0, stream>>>(hnew, out_w, out_b, out, pmax, psum);
  kD<<<(V + 511) / 512, 512, 0, stream>>>(pmax, psum, out);
}

// Round 14
// 57.168 us; speedup vs baseline: 1.1442x; 1.0226x over previous
//
#include <hip/hip_runtime.h>
#include <math.h>

#define H 1024
#define S 20
#define V 50257
#define KC_BLOCKS 512
#define KC_WAVES (KC_BLOCKS * 8)  // 4096 waves

__device__ __forceinline__ float wave_reduce_sum(float v) {
  #pragma unroll
  for (int off = 32; off > 0; off >>= 1)
    v += __shfl_xor(v, off, 64);
  return v;
}

// ============ kA: independent streaming work (32 MB) ============
// b in [0,256):    attention energy -> bpart[S][256]  (batched partials,
//                  independent reduce chains for ILP)
// b in [256,1024): gie[W] = dot(w_ih[W][0:H], embed) + b_ih[W]
// b in [1024,1792): ghv[W] = dot(w_hh[W], hidden) + b_hh[W]
__global__ __launch_bounds__(256) void kA(
    const int* __restrict__ token,
    const float* __restrict__ hidden,
    const float* __restrict__ enc,
    const float* __restrict__ embed_table,
    const float* __restrict__ attn_w,
    const float* __restrict__ attn_b,
    const float* __restrict__ v_w,
    const float* __restrict__ w_ih,
    const float* __restrict__ w_hh,
    const float* __restrict__ b_ih,
    const float* __restrict__ b_hh,
    float* __restrict__ bpart,   // [S][256]
    float* __restrict__ gie,     // [3H]
    float* __restrict__ ghv)     // [3H]
{
  __shared__ float esh[4][S];
  const int t = threadIdx.x;
  const int lane = t & 63;
  const int wv = t >> 6;
  const int b = blockIdx.x;

  if (b < 256) {
    const int j = b * 4 + wv;
    const float* wrow = attn_w + (size_t)j * (2 * H);
    float4 wlo[4], whi[4], hid4[4];
    #pragma unroll
    for (int q = 0; q < 4; ++q) {
      const int idx = lane + 64 * q;
      wlo[q]  = ((const float4*)wrow)[idx];
      whi[q]  = ((const float4*)(wrow + H))[idx];
      hid4[q] = ((const float4*)hidden)[idx];
    }
    // per-lane partials: hp + 20 energies, NO reduces inside the loop
    float hp = 0.f;
    #pragma unroll
    for (int q = 0; q < 4; ++q)
      hp += wlo[q].x * hid4[q].x + wlo[q].y * hid4[q].y +
            wlo[q].z * hid4[q].z + wlo[q].w * hid4[q].w;

    float es[S];
    #pragma unroll
    for (int s = 0; s < S; ++s) {
      const float4* e4 = (const float4*)(enc + s * H);
      float acc = 0.f;
      #pragma unroll
      for (int q = 0; q < 4; ++q) {
        const float4 e = e4[lane + 64 * q];
        acc += whi[q].x * e.x + whi[q].y * e.y + whi[q].z * e.z + whi[q].w * e.w;
      }
      es[s] = acc;
    }

    // 21 independent butterfly chains (ILP hides shuffle latency)
    hp = wave_reduce_sum(hp);
    #pragma unroll
    for (int s = 0; s < S; ++s) es[s] = wave_reduce_sum(es[s]);

    // static lane-select (no dynamic register indexing)
    float myval = 0.f;
    #pragma unroll
    for (int s = 0; s < S; ++s) myval = (lane == s) ? es[s] : myval;

    if (lane < S)
      esh[wv][lane] = tanhf(hp + myval + attn_b[j]) * v_w[j];
    __syncthreads();
    if (wv == 0 && lane < S)
      bpart[lane * 256 + b] =
          esh[0][lane] + esh[1][lane] + esh[2][lane] + esh[3][lane];
  } else if (b < 1024) {
    const int W = (b - 256) * 4 + wv;
    const float* wr = w_ih + (size_t)W * (2 * H);
    const float* embed = embed_table + (size_t)(*token) * H;
    float a = 0.f;
    #pragma unroll
    for (int q = 0; q < 4; ++q) {
      const int idx = lane + 64 * q;
      const float4 w = ((const float4*)wr)[idx];
      const float4 e = ((const float4*)embed)[idx];
      a += w.x * e.x + w.y * e.y + w.z * e.z + w.w * e.w;
    }
    a = wave_reduce_sum(a);
    if (lane == 0) gie[W] = a + b_ih[W];
  } else {
    const int W = (b - 1024) * 4 + wv;
    const float* wr = w_hh + (size_t)W * H;
    float a = 0.f;
    #pragma unroll
    for (int q = 0; q < 4; ++q) {
      const int idx = lane + 64 * q;
      const float4 w = ((const float4*)wr)[idx];
      const float4 h = ((const float4*)hidden)[idx];
      a += w.x * h.x + w.y * h.y + w.z * h.z + w.w * h.w;
    }
    a = wave_reduce_sum(a);
    if (lane == 0) ghv[W] = a + b_hh[W];
  }
}

// ============ kB: redundant softmax+context (vectorized), batched gate dots ==
__global__ __launch_bounds__(256) void kB(
    const float* __restrict__ enc,
    const float* __restrict__ bpart,
    const float* __restrict__ w_ih,
    const float* __restrict__ gie,
    const float* __restrict__ ghv,
    const float* __restrict__ hidden,
    float* __restrict__ hnew,
    float* __restrict__ out)      // out[V..V+H) gets hnew
{
  __shared__ float scores_sh[S];
  __shared__ float attn_sh[S];
  __shared__ float wsh[H];
  const int t = threadIdx.x;
  const int lane = t & 63;
  const int wv = t >> 6;
  const int j = blockIdx.x * 4 + wv;

  for (int s = wv; s < S; s += 4) {
    const float4 p = ((const float4*)(bpart + s * 256))[lane];
    float v = wave_reduce_sum(p.x + p.y + p.z + p.w);
    if (lane == 0) scores_sh[s] = v;
  }
  __syncthreads();
  if (t == 0) {
    float m = -1e30f;
    for (int s = 0; s < S; ++s) m = fmaxf(m, scores_sh[s]);
    float sum = 0.f;
    for (int s = 0; s < S; ++s) {
      const float e = expf(scores_sh[s] - m);
      attn_sh[s] = e;
      sum += e;
    }
    const float inv = 1.f / sum;
    for (int s = 0; s < S; ++s) attn_sh[s] *= inv;
  }
  __syncthreads();

  // context: thread t computes wsh[4t..4t+3] via 20 float4 L2 loads
  {
    float4 acc4 = make_float4(0.f, 0.f, 0.f, 0.f);
    #pragma unroll
    for (int s = 0; s < S; ++s) {
      const float a = attn_sh[s];
      const float4 e = ((const float4*)(enc + s * H))[t];
      acc4.x += a * e.x; acc4.y += a * e.y;
      acc4.z += a * e.z; acc4.w += a * e.w;
    }
    ((float4*)wsh)[t] = acc4;
  }
  __syncthreads();

  float4 c4[4];
  #pragma unroll
  for (int q = 0; q < 4; ++q) c4[q] = ((const float4*)wsh)[lane + 64 * q];

  // batch-load all 3 gate rows (one HBM round-trip), then 3 independent reduces
  float4 wg[3][4];
  #pragma unroll
  for (int g = 0; g < 3; ++g) {
    const float* wr = w_ih + (size_t)(g * H + j) * (2 * H) + H;
    #pragma unroll
    for (int q = 0; q < 4; ++q)
      wg[g][q] = ((const float4*)wr)[lane + 64 * q];
  }
  float gict[3];
  #pragma unroll
  for (int g = 0; g < 3; ++g) {
    float a = 0.f;
    #pragma unroll
    for (int q = 0; q < 4; ++q) {
      const float4 w = wg[g][q];
      a += w.x * c4[q].x + w.y * c4[q].y + w.z * c4[q].z + w.w * c4[q].w;
    }
    gict[g] = a;
  }
  #pragma unroll
  for (int g = 0; g < 3; ++g) gict[g] = wave_reduce_sum(gict[g]);

  if (lane == 0) {
    const float i_r = gie[j]         + gict[0];
    const float i_z = gie[H + j]     + gict[1];
    const float i_n = gie[2 * H + j] + gict[2];
    const float h_r = ghv[j];
    const float h_z = ghv[H + j];
    const float h_n = ghv[2 * H + j];
    const float r = 1.f / (1.f + expf(-(i_r + h_r)));
    const float z = 1.f / (1.f + expf(-(i_z + h_z)));
    const float n = tanhf(i_n + r * h_n);
    const float hn = (1.f - z) * n + z * hidden[j];
    hnew[j] = hn;
    out[V + j] = hn;
  }
}

// ============ kC: balanced-chunk streaming logits, 2 rows/group, hi-occ ======
// (unchanged from round 13 -- best measured config)
__global__ __launch_bounds__(512, 8) void kC(
    const float* __restrict__ hnew,
    const float* __restrict__ out_w,    // [V][H]
    const float* __restrict__ out_b,    // [V]
    float* __restrict__ out,            // logits
    float* __restrict__ pmax,           // [KC_BLOCKS]
    float* __restrict__ psum)           // [KC_BLOCKS]
{
  __shared__ float stat_m[8];
  __shared__ float stat_s[8];
  const int t = threadIdx.x;
  const int lane = t & 63;
  const int wv = t >> 6;
  const int b = blockIdx.x;
  const long long gw = b * 8 + wv;

  float4 h4[4];
  #pragma unroll
  for (int q = 0; q < 4; ++q)
    h4[q] = ((const float4*)hnew)[lane + 64 * q];

  const int r0 = (int)((gw * V) / KC_WAVES);
  const int r1 = (int)(((gw + 1) * V) / KC_WAVES);

  float wm = -INFINITY, wsum = 0.f;

  int r = r0;
  for (; r + 2 <= r1; r += 2) {
    const float4* p0 = (const float4*)(out_w + (size_t)(r + 0) * H);
    const float4* p1 = (const float4*)(out_w + (size_t)(r + 1) * H);
    float a0 = 0.f, a1 = 0.f;
    #pragma unroll
    for (int q = 0; q < 4; ++q) {
      const int idx = lane + 64 * q;
      const float4 w0 = p0[idx];
      const float4 w1 = p1[idx];
      a0 += w0.x * h4[q].x + w0.y * h4[q].y + w0.z * h4[q].z + w0.w * h4[q].w;
      a1 += w1.x * h4[q].x + w1.y * h4[q].y + w1.z * h4[q].z + w1.w * h4[q].w;
    }
    a0 = wave_reduce_sum(a0);
    a1 = wave_reduce_sum(a1);
    const float val0 = a0 + out_b[r + 0];
    const float val1 = a1 + out_b[r + 1];

    const float vv = (lane == 0) ? val0 : val1;
    if (lane < 2) out[r + lane] = vv;

    const float gm = fmaxf(val0, val1);
    const float M2 = fmaxf(wm, gm);
    wsum = wsum * expf(wm - M2) + expf(val0 - M2) + expf(val1 - M2);
    wm = M2;
  }
  for (; r < r1; ++r) {
    const float4* p0 = (const float4*)(out_w + (size_t)r * H);
    float a0 = 0.f;
    #pragma unroll
    for (int q = 0; q < 4; ++q) {
      const float4 w0 = p0[lane + 64 * q];
      a0 += w0.x * h4[q].x + w0.y * h4[q].y + w0.z * h4[q].z + w0.w * h4[q].w;
    }
    a0 = wave_reduce_sum(a0);
    const float val0 = a0 + out_b[r];
    if (lane == 0) out[r] = val0;
    const float M2 = fmaxf(wm, val0);
    wsum = wsum * expf(wm - M2) + expf(val0 - M2);
    wm = M2;
  }

  if (lane == 0) { stat_m[wv] = wm; stat_s[wv] = wsum; }
  __syncthreads();
  if (t == 0) {
    float M = stat_m[0], Ss = stat_s[0];
    #pragma unroll
    for (int i = 1; i < 8; ++i) {
      const float m2 = stat_m[i], s2 = stat_s[i];
      const float M2 = fmaxf(M, m2);
      Ss = Ss * expf(M - M2) + s2 * expf(m2 - M2);
      M = M2;
    }
    pmax[b] = M;
    psum[b] = Ss;
  }
}

// ============ kD: block-redundant stat reduce + subtract ============
__global__ __launch_bounds__(512) void kD(
    const float* __restrict__ pmax,
    const float* __restrict__ psum,
    float* __restrict__ out)
{
  __shared__ float sm[8];
  __shared__ float ss[8];
  __shared__ float Tsh;
  const int t = threadIdx.x, lane = t & 63, wv = t >> 6;

  float dm = pmax[t];
  float dsv = psum[t];
  #pragma unroll
  for (int off = 32; off > 0; off >>= 1) {
    const float m2 = __shfl_xor(dm, off, 64);
    const float s2 = __shfl_xor(dsv, off, 64);
    const float M2 = fmaxf(dm, m2);
    dsv = dsv * expf(dm - M2) + s2 * expf(m2 - M2);
    dm = M2;
  }
  if (lane == 0) { sm[wv] = dm; ss[wv] = dsv; }
  __syncthreads();
  if (t == 0) {
    float M = sm[0], Ss = ss[0];
    #pragma unroll
    for (int i = 1; i < 8; ++i) {
      const float m2 = sm[i], s2 = ss[i];
      const float M2 = fmaxf(M, m2);
      Ss = Ss * expf(M - M2) + s2 * expf(m2 - M2);
      M = M2;
    }
    Tsh = M + logf(Ss);
  }
  __syncthreads();
  const float T = Tsh;
  const int i = blockIdx.x * 512 + t;
  if (i < V) out[i] -= T;
}

extern "C" void kernel_launch(void* const* d_in, const int* in_sizes, int n_in,
                              void* d_out, int out_size, void* d_ws, size_t ws_size,
                              hipStream_t stream) {
  const int*   token       = (const int*)d_in[0];
  const float* hidden      = (const float*)d_in[1];
  const float* enc         = (const float*)d_in[2];
  const float* embed_table = (const float*)d_in[3];
  const float* attn_w      = (const float*)d_in[4];
  const float* attn_b      = (const float*)d_in[5];
  const float* v_w         = (const float*)d_in[6];
  const float* w_ih        = (const float*)d_in[7];
  const float* w_hh        = (const float*)d_in[8];
  const float* b_ih        = (const float*)d_in[9];
  const float* b_hh        = (const float*)d_in[10];
  const float* out_w       = (const float*)d_in[11];
  const float* out_b       = (const float*)d_in[12];
  float* out = (float*)d_out;
  float* ws  = (float*)d_ws;

  // ws layout (floats)
  float* bpart = ws;           // 5120
  float* gie   = ws + 5120;    // 3072
  float* ghv   = ws + 8192;    // 3072
  float* hnew  = ws + 11264;   // 1024
  float* pmax  = ws + 12288;   // 512
  float* psum  = ws + 12800;   // 512

  kA<<<1792, 256, 0, stream>>>(token, hidden, enc, embed_table, attn_w, attn_b,
                               v_w, w_ih, w_hh, b_ih, b_hh, bpart, gie, ghv);
  kB<<<256, 256, 0, stream>>>(enc, bpart, w_ih, gie, ghv, hidden, hnew, out);
  kC<<<KC_BLOCKS, 512, 0, stream>>>(hnew, out_w, out_b, out, pmax, psum);
  kD<<<(V + 511) / 512, 512, 0, stream>>>(pmax, psum, out);
}